// Round 2
// baseline (1277.283 us; speedup 1.0000x reference)
//
#include <hip/hip_runtime.h>
#include <stdint.h>

// Monarch attention, B=4 H=16 N=8192 D=64, b=128, m=64, T=3.
// Split-bf16 MFMA (hi+lo, 3 mfma per product) ~= fp32 precision at matrix-core rate.
// v3: conflict-free universal XOR swizzle (no pad), LDS shrink (r:52KB/3blk, out:26.6KB/6blk),
//     direct-global A/B fragments where wave-private or L1-resident, pack-once Kpk/Qpk
//     (ws_size-guarded with exact v2-footprint fallback).

#define BH   64
#define NTOK 8192
#define DD   64
#define MM   64
#define BBS  128

typedef __attribute__((ext_vector_type(8))) short bf16x8;
typedef __attribute__((ext_vector_type(4))) float f32x4;

union U8 { bf16x8 v; uint32_t u[4]; };

__device__ __forceinline__ f32x4 MF(bf16x8 a, bf16x8 b, f32x4 c){
    return __builtin_amdgcn_mfma_f32_16x16x32_bf16(a, b, c, 0, 0, 0);
}
__device__ __forceinline__ f32x4 MF3(bf16x8 ah, bf16x8 al, bf16x8 bh_, bf16x8 bl_, f32x4 c){
    c = MF(ah, bh_, c);
    c = MF(ah, bl_, c);
    c = MF(al, bh_, c);
    return c;
}

__device__ __forceinline__ ushort bf16h(float x){
    union{float f; uint32_t u;} v; v.f = x;
    return (ushort)((v.u + 0x7fffu + ((v.u >> 16) & 1u)) >> 16);
}
__device__ __forceinline__ float bf16f(ushort h){
    union{float f; uint32_t u;} v; v.u = ((uint32_t)h) << 16; return v.f;
}
__device__ __forceinline__ void split2(float x, ushort& h, ushort& l){
    h = bf16h(x);
    l = bf16h(x - bf16f(h));
}
__device__ __forceinline__ uint32_t packsplit(float x){
    ushort h, l; split2(x, h, l);
    return ((uint32_t)h << 16) | (uint32_t)l;
}
__device__ __forceinline__ void st2(ushort* p, ushort a, ushort b){
    *(uint32_t*)p = (uint32_t)a | ((uint32_t)b << 16);
}
__device__ __forceinline__ void up2(uint32_t w0, uint32_t w1, uint32_t& hw, uint32_t& lw){
    hw = (w0 >> 16)     | (w1 & 0xffff0000u);
    lw = (w0 & 0xffffu) | (w1 << 16);
}
__device__ __forceinline__ void pack2(float a, float b, uint32_t& hw, uint32_t& lw){
    ushort ah_, al_, bh2, bl2;
    split2(a, ah_, al_); split2(b, bh2, bl2);
    hw = (uint32_t)ah_ | ((uint32_t)bh2 << 16);
    lw = (uint32_t)al_ | ((uint32_t)bl2 << 16);
}
// universal bank swizzle: XOR offset (ushorts, multiple of 8). Verified conflict-free for
// row-constant 16-lane write phases, row=4s+q transpose writes, and rows c*16+n b128 reads.
__device__ __forceinline__ int swz8(int row){
    return ((((row & 3) << 1) ^ ((row >> 2) & 7)) << 3);
}
__device__ __forceinline__ void frag_pk(uint4 a, uint4 b, bf16x8& h, bf16x8& l){
    U8 H, L;
    up2(a.x,a.y,H.u[0],L.u[0]); up2(a.z,a.w,H.u[1],L.u[1]);
    up2(b.x,b.y,H.u[2],L.u[2]); up2(b.z,b.w,H.u[3],L.u[3]);
    h = H.v; l = L.v;
}

__device__ __forceinline__ float red16_max(float v){
    v = fmaxf(v, __shfl_xor(v, 1));
    v = fmaxf(v, __shfl_xor(v, 2));
    v = fmaxf(v, __shfl_xor(v, 4));
    v = fmaxf(v, __shfl_xor(v, 8));
    return v;
}
__device__ __forceinline__ float red16_sum(float v){
    v += __shfl_xor(v, 1);
    v += __shfl_xor(v, 2);
    v += __shfl_xor(v, 4);
    v += __shfl_xor(v, 8);
    return v;
}

// 4x4 transpose among quad lanes {t, t^16, t^32, t^48}; qpos = (lane>>4)&3.
// In: x_c = X[qpos][c].  Out: z_c = X[c][qpos].  (u32 payload)
__device__ __forceinline__ void tr4x4u(int qpos, uint32_t x0, uint32_t x1, uint32_t x2, uint32_t x3,
                                       uint32_t& z0, uint32_t& z1, uint32_t& z2, uint32_t& z3){
    uint32_t s1 = (qpos&1) ? x0 : x1; uint32_t g1 = (uint32_t)__shfl_xor((int)s1, 16);
    uint32_t s2 = (qpos&1) ? x2 : x3; uint32_t g2 = (uint32_t)__shfl_xor((int)s2, 16);
    uint32_t y0 = (qpos&1) ? g1 : x0;
    uint32_t y1 = (qpos&1) ? x1 : g1;
    uint32_t y2 = (qpos&1) ? g2 : x2;
    uint32_t y3 = (qpos&1) ? x3 : g2;
    uint32_t u1 = (qpos&2) ? y0 : y2; uint32_t h1 = (uint32_t)__shfl_xor((int)u1, 32);
    uint32_t u2 = (qpos&2) ? y1 : y3; uint32_t h2 = (uint32_t)__shfl_xor((int)u2, 32);
    z0 = (qpos&2) ? h1 : y0;
    z2 = (qpos&2) ? y2 : h1;
    z1 = (qpos&2) ? h2 : y1;
    z3 = (qpos&2) ? y3 : h2;
}

// ---- Kbar0[bh][k][d] = mean over l' of K (packed); also emit packed-split Kpk ----
__global__ __launch_bounds__(256) void kbar0_kernel(const float* __restrict__ K,
                                                    uint32_t* __restrict__ kbar0p,
                                                    uint32_t* __restrict__ kpk){
    const int k = blockIdx.x, bh = blockIdx.y;
    const int t = threadIdx.x;
    const int d = t & 63, p = t >> 6;
    __shared__ float part[4][64];
    const float* base = K + ((size_t)bh*NTOK + (size_t)k*BBS)*DD + d;
    uint32_t* kpb = kpk ? kpk + ((size_t)bh*NTOK + (size_t)k*BBS)*DD + d : nullptr;
    float s = 0.f;
    for(int lp = p*32; lp < p*32 + 32; ++lp){
        float v = base[(size_t)lp*DD];
        s += v;
        if(kpb) kpb[(size_t)lp*DD] = packsplit(v);
    }
    part[p][d] = s;
    __syncthreads();
    if(t < 64){
        float tot = part[0][t] + part[1][t] + part[2][t] + part[3][t];
        kbar0p[((size_t)bh*MM + k)*DD + t] = packsplit(tot * (1.0f/128.0f));
    }
}

// ---- L-step: per (bh,l). S=Q Kbar^T, softmax_k -> L, Qbar = L^T Q / (w+eps) ----
// A1 direct-global (wave-private Q rows); B1 direct-global packed kbar (L1-reused);
// sQT staged via shfl transpose (swz8); sLT shared for GEMM2. 33KB LDS, 2 syncs.
__global__ __launch_bounds__(256, 4) void l_kernel(const float* __restrict__ Q,
                                                   const uint32_t* __restrict__ kb_in,
                                                   int mode,
                                                   const uint32_t* __restrict__ qpk_ld,
                                                   uint32_t* __restrict__ qpk_st,
                                                   uint32_t* __restrict__ qbar){
    const int l = blockIdx.x, bh = blockIdx.y;
    const int t = threadIdx.x;
    __shared__ __align__(16) ushort sQTh[4096], sQTl[4096];
    __shared__ __align__(16) ushort sLTh[4096], sLTl[4096];
    __shared__ float wsum[64];

    const int lane = t & 63, wv = t >> 6;
    const int n = lane & 15, qd = lane >> 4;
    const int m0 = wv * 16;

    if(t < 64) wsum[t] = 0.f;

    // A-fragments: Q rows m0+n (wave-private), direct from global
    U8 ah0, al0, ah1, al1;
    const size_t qoff = ((size_t)bh*NTOK + (size_t)(m0+n)*BBS + l)*DD;
    if(qpk_ld){
        uint4 a0 = *(const uint4*)(qpk_ld + qoff + qd*8);
        uint4 a1 = *(const uint4*)(qpk_ld + qoff + qd*8 + 4);
        uint4 a2 = *(const uint4*)(qpk_ld + qoff + 32 + qd*8);
        uint4 a3 = *(const uint4*)(qpk_ld + qoff + 32 + qd*8 + 4);
        up2(a0.x,a0.y,ah0.u[0],al0.u[0]); up2(a0.z,a0.w,ah0.u[1],al0.u[1]);
        up2(a1.x,a1.y,ah0.u[2],al0.u[2]); up2(a1.z,a1.w,ah0.u[3],al0.u[3]);
        up2(a2.x,a2.y,ah1.u[0],al1.u[0]); up2(a2.z,a2.w,ah1.u[1],al1.u[1]);
        up2(a3.x,a3.y,ah1.u[2],al1.u[2]); up2(a3.z,a3.w,ah1.u[3],al1.u[3]);
    } else {
        float4 qv0 = *(const float4*)(Q + qoff + qd*8);
        float4 qv1 = *(const float4*)(Q + qoff + qd*8 + 4);
        float4 qv2 = *(const float4*)(Q + qoff + 32 + qd*8);
        float4 qv3 = *(const float4*)(Q + qoff + 32 + qd*8 + 4);
        pack2(qv0.x,qv0.y,ah0.u[0],al0.u[0]); pack2(qv0.z,qv0.w,ah0.u[1],al0.u[1]);
        pack2(qv1.x,qv1.y,ah0.u[2],al0.u[2]); pack2(qv1.z,qv1.w,ah0.u[3],al0.u[3]);
        pack2(qv2.x,qv2.y,ah1.u[0],al1.u[0]); pack2(qv2.z,qv2.w,ah1.u[1],al1.u[1]);
        pack2(qv3.x,qv3.y,ah1.u[2],al1.u[2]); pack2(qv3.z,qv3.w,ah1.u[3],al1.u[3]);
    }

    // stage Q^T (shfl transpose, swz8); optionally emit Qpk
    const int w4 = t >> 4, qpos = w4 & 3, dq = (t & 15) << 2;
    #pragma unroll
    for(int j=0;j<4;++j){
        int i  = j*16 + w4;
        int ib = j*16 + (w4 & ~3);
        size_t off = ((size_t)bh*NTOK + (size_t)i*BBS + l)*DD + dq;
        uint32_t p0,p1,p2,p3v;
        if(qpk_ld){
            uint4 u = *(const uint4*)(qpk_ld + off);
            p0=u.x; p1=u.y; p2=u.z; p3v=u.w;
        } else {
            float4 v = *(const float4*)(Q + off);
            p0=packsplit(v.x); p1=packsplit(v.y); p2=packsplit(v.z); p3v=packsplit(v.w);
            if(qpk_st){
                uint4 uu; uu.x=p0; uu.y=p1; uu.z=p2; uu.w=p3v;
                *(uint4*)(qpk_st + off) = uu;
            }
        }
        uint32_t z0,z1,z2,z3;
        tr4x4u(qpos, p0,p1,p2,p3v, z0,z1,z2,z3);   // z_c = Qpk[ib+c][dq+qpos]
        int rowd = dq + qpos;
        int e = rowd*64 + (ib ^ swz8(rowd));
        st2(&sQTh[e],   (ushort)(z0>>16), (ushort)(z1>>16));
        st2(&sQTh[e+2], (ushort)(z2>>16), (ushort)(z3>>16));
        st2(&sQTl[e],   (ushort)(z0&0xffffu), (ushort)(z1&0xffffu));
        st2(&sQTl[e+2], (ushort)(z2&0xffffu), (ushort)(z3&0xffffu));
    }
    __syncthreads();   // wsum zero + (early) sQT drain

    // GEMM1: S = Q Kbar^T (64x64, K=64); B direct from packed global (L1-resident 16KB)
    const uint32_t* kb_base = mode ? kb_in + ((size_t)bh*BBS + l)*(size_t)(MM*DD)
                                   : kb_in + (size_t)bh*(size_t)(MM*DD);
    f32x4 accS[4] = {};
    #pragma unroll
    for(int kb=0;kb<2;++kb){
        bf16x8 ah = kb ? ah1.v : ah0.v;
        bf16x8 al = kb ? al1.v : al0.v;
        #pragma unroll
        for(int c=0;c<4;++c){
            const uint32_t* fp = kb_base + (size_t)(c*16+n)*DD + kb*32 + qd*8;
            uint4 b0 = *(const uint4*)fp;
            uint4 b1 = *(const uint4*)(fp + 4);
            bf16x8 bh_, bl_; frag_pk(b0, b1, bh_, bl_);
            accS[c] = MF3(ah, al, bh_, bl_, accS[c]);
        }
    }

    // softmax rows -> write L^T (swz8), col-sums
    float colp[4] = {0.f,0.f,0.f,0.f};
    #pragma unroll
    for(int r=0;r<4;++r){
        float vals[4]; float mx = -3.4e38f;
        #pragma unroll
        for(int c=0;c<4;++c){ vals[c] = accS[c][r]*0.125f; mx = fmaxf(mx, vals[c]); }
        mx = red16_max(mx);
        float s = 0.f;
        #pragma unroll
        for(int c=0;c<4;++c){ vals[c] = __expf(vals[c]-mx); s += vals[c]; }
        s = red16_sum(s);
        float inv = 1.0f/s;
        int irow = m0 + qd*4 + r;
        #pragma unroll
        for(int c=0;c<4;++c){
            float Lv = vals[c]*inv;
            colp[c] += Lv;
            ushort hh, ll; split2(Lv, hh, ll);
            int row = c*16+n;
            sLTh[row*64 + (irow ^ swz8(row))] = hh;
            sLTl[row*64 + (irow ^ swz8(row))] = ll;
        }
    }
    #pragma unroll
    for(int c=0;c<4;++c){
        float v = colp[c];
        v += __shfl_xor(v,16); v += __shfl_xor(v,32);
        if(qd == 0) atomicAdd(&wsum[c*16+n], v);
    }
    __syncthreads();

    // GEMM2: Qbar[k][d] = sum_i L^T[k][i] Q[i][d]
    f32x4 accQ[4] = {};
    #pragma unroll
    for(int kb=0;kb<2;++kb){
        int co = kb*32 + qd*8;
        int ra = m0 + n;
        bf16x8 ah = *(const bf16x8*)&sLTh[ra*64 + (co ^ swz8(ra))];
        bf16x8 al = *(const bf16x8*)&sLTl[ra*64 + (co ^ swz8(ra))];
        #pragma unroll
        for(int dt2=0;dt2<4;++dt2){
            int rb = dt2*16 + n;
            bf16x8 bh_ = *(const bf16x8*)&sQTh[rb*64 + (co ^ swz8(rb))];
            bf16x8 bl_ = *(const bf16x8*)&sQTl[rb*64 + (co ^ swz8(rb))];
            accQ[dt2] = MF3(ah, al, bh_, bl_, accQ[dt2]);
        }
    }
    uint32_t* qb = qbar + ((size_t)bh*BBS + l)*(size_t)(MM*DD);
    #pragma unroll
    for(int r=0;r<4;++r){
        int krow = m0 + qd*4 + r;
        float invw = 1.0f/(wsum[krow] + 1e-6f);
        #pragma unroll
        for(int dt2=0;dt2<4;++dt2){
            qb[(size_t)krow*DD + dt2*16 + n] = packsplit(accQ[dt2][r]*invw);
        }
    }
}

// ---- R-step: per (bh,k), 512 thr. S=Qbar K^T (128x128), softmax -> R,
//      out = R @ K (kbar) or R @ V (Vbar into d_out tokens).
// 52KB LDS -> 3 blocks/CU. X1 (K) and XT (X2^T) time-share 32KB; SW wave-local 20KB.
__global__ __launch_bounds__(512, 6) void r_kernel(const uint32_t* __restrict__ qbar,
                                                   const float* __restrict__ K,
                                                   const uint32_t* __restrict__ kpk,
                                                   const float* __restrict__ V,
                                                   uint32_t* __restrict__ outp, int outTok){
    const int k = blockIdx.x, bh = blockIdx.y;
    const int t = threadIdx.x;
    __shared__ __align__(16) ushort sm[26624];   // 52 KiB
    ushort* X1h = sm;            // [128][64] swz8   (later aliased: XTh [64][128] swz8)
    ushort* X1l = sm + 8192;

    const int lane = t & 63, wv = t >> 6;
    const int n = lane & 15, qd = lane >> 4;
    const int m0 = wv * 16;

    // A-fragment loads (qbar rows m0+n wave-private) -- issue first
    const uint32_t* qrow = qbar + (size_t)bh*BBS*(size_t)(MM*DD)
                         + (size_t)(m0+n)*(size_t)(MM*DD) + (size_t)k*DD;
    uint4 qa0 = *(const uint4*)(qrow + qd*8);
    uint4 qa1 = *(const uint4*)(qrow + qd*8 + 4);
    uint4 qa2 = *(const uint4*)(qrow + 32 + qd*8);
    uint4 qa3 = *(const uint4*)(qrow + 32 + qd*8 + 4);

    // stage X1 = K (split, swz8 row-major). Row-constant 16-lane phases -> all-32-bank writes.
    const int w4 = t >> 4, qpos = w4 & 3, dq = (t & 15) << 2;
    const size_t kboff = ((size_t)bh*NTOK + (size_t)k*BBS)*DD;
    #pragma unroll
    for(int j=0;j<4;++j){
        int lp = j*32 + w4;
        uint32_t p0,p1,p2,p3v;
        if(kpk){
            uint4 u = *(const uint4*)(kpk + kboff + (size_t)lp*DD + dq);
            p0=u.x; p1=u.y; p2=u.z; p3v=u.w;
        } else {
            float4 v = *(const float4*)(K + kboff + (size_t)lp*DD + dq);
            p0=packsplit(v.x); p1=packsplit(v.y); p2=packsplit(v.z); p3v=packsplit(v.w);
        }
        int e = lp*64 + (dq ^ swz8(lp));
        *(uint32_t*)&X1h[e]   = (p0>>16)     | (p1 & 0xffff0000u);
        *(uint32_t*)&X1h[e+2] = (p2>>16)     | (p3v & 0xffff0000u);
        *(uint32_t*)&X1l[e]   = (p0&0xffffu) | (p1 << 16);
        *(uint32_t*)&X1l[e+2] = (p2&0xffffu) | (p3v << 16);
    }
    __syncthreads();

    // unpack A fragments
    U8 ah0, al0, ah1, al1;
    up2(qa0.x,qa0.y,ah0.u[0],al0.u[0]); up2(qa0.z,qa0.w,ah0.u[1],al0.u[1]);
    up2(qa1.x,qa1.y,ah0.u[2],al0.u[2]); up2(qa1.z,qa1.w,ah0.u[3],al0.u[3]);
    up2(qa2.x,qa2.y,ah1.u[0],al1.u[0]); up2(qa2.z,qa2.w,ah1.u[1],al1.u[1]);
    up2(qa3.x,qa3.y,ah1.u[2],al1.u[2]); up2(qa3.z,qa3.w,ah1.u[3],al1.u[3]);

    // GEMM1: S = Qbar K^T (128x128, K-dim 64); conflict-free b128 reads
    f32x4 accS[8] = {};
    #pragma unroll
    for(int c=0;c<8;++c){
        int row = c*16 + n;
        int bb = row*64, sw = swz8(row);
        bf16x8 bh_ = *(const bf16x8*)&X1h[bb + ((qd*8) ^ sw)];
        bf16x8 bl_ = *(const bf16x8*)&X1l[bb + ((qd*8) ^ sw)];
        accS[c] = MF3(ah0.v, al0.v, bh_, bl_, accS[c]);
        bh_ = *(const bf16x8*)&X1h[bb + ((32 + qd*8) ^ sw)];
        bl_ = *(const bf16x8*)&X1l[bb + ((32 + qd*8) ^ sw)];
        accS[c] = MF3(ah1.v, al1.v, bh_, bl_, accS[c]);
    }

    // softmax rows over 128 cols; probabilities stay in accS
    #pragma unroll
    for(int r=0;r<4;++r){
        float vals[8]; float mx = -3.4e38f;
        #pragma unroll
        for(int c=0;c<8;++c){ vals[c] = accS[c][r]*0.125f; mx = fmaxf(mx, vals[c]); }
        mx = red16_max(mx);
        float s = 0.f;
        #pragma unroll
        for(int c=0;c<8;++c){ vals[c] = __expf(vals[c]-mx); s += vals[c]; }
        s = red16_sum(s);
        float inv = 1.0f/s;
        #pragma unroll
        for(int c=0;c<8;++c) accS[c][r] = vals[c]*inv;
    }
    __syncthreads();   // all waves done reading X1 -> reuse as XT

    // stage XT = (V ? V : K)^T into the X1 region (shfl transpose, swz8)
    ushort* XTh = sm;            // [64][128] swz8
    ushort* XTl = sm + 8192;
    #pragma unroll
    for(int j=0;j<4;++j){
        int lp = j*32 + w4;
        uint32_t p0,p1,p2,p3v;
        if(V){
            float4 v = *(const float4*)(V + kboff + (size_t)lp*DD + dq);
            p0=packsplit(v.x); p1=packsplit(v.y); p2=packsplit(v.z); p3v=packsplit(v.w);
        } else if(kpk){
            uint4 u = *(const uint4*)(kpk + kboff + (size_t)lp*DD + dq);   // L1-hot
            p0=u.x; p1=u.y; p2=u.z; p3v=u.w;
        } else {
            float4 v = *(const float4*)(K + kboff + (size_t)lp*DD + dq);   // L1-hot
            p0=packsplit(v.x); p1=packsplit(v.y); p2=packsplit(v.z); p3v=packsplit(v.w);
        }
        uint32_t z0,z1,z2,z3;
        tr4x4u(qpos, p0,p1,p2,p3v, z0,z1,z2,z3);   // z_c = X2[lb+c][dq+qpos]
        int dv = dq + qpos;
        int lb = j*32 + (w4 & ~3);
        int e = dv*128 + (lb ^ swz8(dv));
        *(uint32_t*)&XTh[e]   = (z0>>16)     | (z1 & 0xffff0000u);
        *(uint32_t*)&XTh[e+2] = (z2>>16)     | (z3 & 0xffff0000u);
        *(uint32_t*)&XTl[e]   = (z0&0xffffu) | (z1 << 16);
        *(uint32_t*)&XTl[e+2] = (z2&0xffffu) | (z3 << 16);
    }
    __syncthreads();

    // GEMM2: Out[l][d] = sum_{l'} R[l][l'] X2[l'][d], 4 chunks of 32; R wave-local via SW
    ushort* SWh = sm + 16384 + wv*1280;   // [16][40] hi
    ushort* SWl = SWh + 640;              // [16][40] lo
    const int sw_rd = n*40 + qd*8;
    f32x4 accO[4] = {};
    #pragma unroll
    for(int kb=0;kb<4;++kb){
        #pragma unroll
        for(int r=0;r<4;++r){
            #pragma unroll
            for(int c2=0;c2<2;++c2){
                ushort hh, ll;
                split2(accS[2*kb+c2][r], hh, ll);
                SWh[(qd*4+r)*40 + c2*16 + n] = hh;
                SWl[(qd*4+r)*40 + c2*16 + n] = ll;
            }
        }
        asm volatile("s_waitcnt lgkmcnt(0)" ::: "memory");  // wave-local write->read
        __builtin_amdgcn_sched_barrier(0);
        bf16x8 ah2 = *(const bf16x8*)&SWh[sw_rd];
        bf16x8 al2 = *(const bf16x8*)&SWl[sw_rd];
        #pragma unroll
        for(int dt2=0;dt2<4;++dt2){
            int row = dt2*16 + n;
            int e2 = row*128 + ((kb*32 + qd*8) ^ swz8(row));
            bf16x8 bh_ = *(const bf16x8*)&XTh[e2];
            bf16x8 bl_ = *(const bf16x8*)&XTl[e2];
            accO[dt2] = MF3(ah2, al2, bh_, bl_, accO[dt2]);
        }
        asm volatile("" ::: "memory");   // keep next chunk's writes after this chunk's reads
    }
    #pragma unroll
    for(int r=0;r<4;++r){
        int lrow = m0 + qd*4 + r;
        #pragma unroll
        for(int dt2=0;dt2<4;++dt2){
            uint32_t pw = packsplit(accO[dt2][r]);
            size_t off = outTok
                ? ((size_t)bh*NTOK + (size_t)k*BBS + lrow)*DD + dt2*16 + n
                : (((size_t)bh*BBS + lrow)*(size_t)MM + k)*DD + dt2*16 + n;
            outp[off] = pw;
        }
    }
}

// ---- Out: per (bh,l). Recompute L3 from (Q,Kbar2) with direct-global A/B;
//      L kept wave-local (SW chunks); out = L3 @ Vbar. 26.6KB LDS -> 6 blocks/CU, 1 sync.
__global__ __launch_bounds__(256, 4) void out_kernel(const float* __restrict__ Q,
                                                     const uint32_t* __restrict__ qpk_ld,
                                                     const uint32_t* __restrict__ kbar,
                                                     float* __restrict__ out){
    const int l = blockIdx.x, bh = blockIdx.y;
    const int t = threadIdx.x;
    __shared__ __align__(16) ushort sVTh[4096], sVTl[4096];
    __shared__ __align__(16) ushort swb[5120];

    const int lane = t & 63, wv = t >> 6;
    const int n = lane & 15, qd = lane >> 4;
    const int m0 = wv * 16;

    // A-fragments: Q rows m0+n direct from global
    U8 ah0, al0, ah1, al1;
    const size_t qoff = ((size_t)bh*NTOK + (size_t)(m0+n)*BBS + l)*DD;
    if(qpk_ld){
        uint4 a0 = *(const uint4*)(qpk_ld + qoff + qd*8);
        uint4 a1 = *(const uint4*)(qpk_ld + qoff + qd*8 + 4);
        uint4 a2 = *(const uint4*)(qpk_ld + qoff + 32 + qd*8);
        uint4 a3 = *(const uint4*)(qpk_ld + qoff + 32 + qd*8 + 4);
        up2(a0.x,a0.y,ah0.u[0],al0.u[0]); up2(a0.z,a0.w,ah0.u[1],al0.u[1]);
        up2(a1.x,a1.y,ah0.u[2],al0.u[2]); up2(a1.z,a1.w,ah0.u[3],al0.u[3]);
        up2(a2.x,a2.y,ah1.u[0],al1.u[0]); up2(a2.z,a2.w,ah1.u[1],al1.u[1]);
        up2(a3.x,a3.y,ah1.u[2],al1.u[2]); up2(a3.z,a3.w,ah1.u[3],al1.u[3]);
    } else {
        float4 qv0 = *(const float4*)(Q + qoff + qd*8);
        float4 qv1 = *(const float4*)(Q + qoff + qd*8 + 4);
        float4 qv2 = *(const float4*)(Q + qoff + 32 + qd*8);
        float4 qv3 = *(const float4*)(Q + qoff + 32 + qd*8 + 4);
        pack2(qv0.x,qv0.y,ah0.u[0],al0.u[0]); pack2(qv0.z,qv0.w,ah0.u[1],al0.u[1]);
        pack2(qv1.x,qv1.y,ah0.u[2],al0.u[2]); pack2(qv1.z,qv1.w,ah0.u[3],al0.u[3]);
        pack2(qv2.x,qv2.y,ah1.u[0],al1.u[0]); pack2(qv2.z,qv2.w,ah1.u[1],al1.u[1]);
        pack2(qv3.x,qv3.y,ah1.u[2],al1.u[2]); pack2(qv3.z,qv3.w,ah1.u[3],al1.u[3]);
    }

    // stage Vbar^T (packed in d_out at tokens kk*b + l) via shfl transpose, swz8
    const int w4 = t >> 4, qpos = w4 & 3, dq = (t & 15) << 2;
    const uint32_t* vb = (const uint32_t*)out;
    #pragma unroll
    for(int j=0;j<4;++j){
        int kk = j*16 + w4;
        uint4 u = *(const uint4*)(vb + ((size_t)bh*NTOK + (size_t)kk*BBS + l)*DD + dq);
        uint32_t z0,z1,z2,z3;
        tr4x4u(qpos, u.x,u.y,u.z,u.w, z0,z1,z2,z3);   // z_c = Vbar[kb4+c][dq+qpos]
        int dv = dq + qpos;
        int kb4 = j*16 + (w4 & ~3);
        int e = dv*64 + (kb4 ^ swz8(dv));
        st2(&sVTh[e],   (ushort)(z0>>16), (ushort)(z1>>16));
        st2(&sVTh[e+2], (ushort)(z2>>16), (ushort)(z3>>16));
        st2(&sVTl[e],   (ushort)(z0&0xffffu), (ushort)(z1&0xffffu));
        st2(&sVTl[e+2], (ushort)(z2&0xffffu), (ushort)(z3&0xffffu));
    }

    // GEMM1: S = Q Kbar^T; B direct from packed kbar (L1-resident 16KB)
    const uint32_t* kb_base = kbar + ((size_t)bh*BBS + l)*(size_t)(MM*DD);
    f32x4 accS[4] = {};
    #pragma unroll
    for(int kb=0;kb<2;++kb){
        bf16x8 ah = kb ? ah1.v : ah0.v;
        bf16x8 al = kb ? al1.v : al0.v;
        #pragma unroll
        for(int c=0;c<4;++c){
            const uint32_t* fp = kb_base + (size_t)(c*16+n)*DD + kb*32 + qd*8;
            uint4 b0 = *(const uint4*)fp;
            uint4 b1 = *(const uint4*)(fp + 4);
            bf16x8 bh_, bl_; frag_pk(b0, b1, bh_, bl_);
            accS[c] = MF3(ah, al, bh_, bl_, accS[c]);
        }
    }

    // softmax -> L stays in accS (wave-local rows)
    #pragma unroll
    for(int r=0;r<4;++r){
        float vals[4]; float mx = -3.4e38f;
        #pragma unroll
        for(int c=0;c<4;++c){ vals[c] = accS[c][r]*0.125f; mx = fmaxf(mx, vals[c]); }
        mx = red16_max(mx);
        float s = 0.f;
        #pragma unroll
        for(int c=0;c<4;++c){ vals[c] = __expf(vals[c]-mx); s += vals[c]; }
        s = red16_sum(s);
        float inv = 1.0f/s;
        #pragma unroll
        for(int c=0;c<4;++c) accS[c][r] = vals[c]*inv;
    }
    __syncthreads();   // sVT ready

    // GEMM2: O[i][d] = sum_k L[i][k] Vbar[k][d], 2 chunks of 32; L wave-local via SW
    ushort* SWh = swb + wv*1280;
    ushort* SWl = SWh + 640;
    const int sw_rd = n*40 + qd*8;
    f32x4 accO[4] = {};
    #pragma unroll
    for(int kb=0;kb<2;++kb){
        #pragma unroll
        for(int r=0;r<4;++r){
            #pragma unroll
            for(int c2=0;c2<2;++c2){
                ushort hh, ll;
                split2(accS[2*kb+c2][r], hh, ll);
                SWh[(qd*4+r)*40 + c2*16 + n] = hh;
                SWl[(qd*4+r)*40 + c2*16 + n] = ll;
            }
        }
        asm volatile("s_waitcnt lgkmcnt(0)" ::: "memory");
        __builtin_amdgcn_sched_barrier(0);
        bf16x8 ah2 = *(const bf16x8*)&SWh[sw_rd];
        bf16x8 al2 = *(const bf16x8*)&SWl[sw_rd];
        #pragma unroll
        for(int dt2=0;dt2<4;++dt2){
            int row = dt2*16 + n;
            int e2 = row*64 + ((kb*32 + qd*8) ^ swz8(row));
            bf16x8 bh_ = *(const bf16x8*)&sVTh[e2];
            bf16x8 bl_ = *(const bf16x8*)&sVTl[e2];
            accO[dt2] = MF3(ah2, al2, bh_, bl_, accO[dt2]);
        }
        asm volatile("" ::: "memory");
    }
    #pragma unroll
    for(int r=0;r<4;++r){
        int irow = m0 + qd*4 + r;
        #pragma unroll
        for(int dt2=0;dt2<4;++dt2){
            out[((size_t)bh*NTOK + (size_t)irow*BBS + l)*DD + dt2*16 + n] = accO[dt2][r];
        }
    }
}

extern "C" void kernel_launch(void* const* d_in, const int* in_sizes, int n_in,
                              void* d_out, int out_size, void* d_ws, size_t ws_size,
                              hipStream_t stream){
    const float* Q = (const float*)d_in[0];
    const float* K = (const float*)d_in[1];
    const float* V = (const float*)d_in[2];
    float* out = (float*)d_out;
    const size_t big = (size_t)BH * BBS * MM * DD;     // 33,554,432
    const size_t kb0sz = (size_t)BH * MM * DD;         // 262,144
    uint32_t* qbar   = (uint32_t*)d_ws;
    uint32_t* kbar   = qbar + big;
    uint32_t* kbar0p = kbar + big;                     // base footprint = v2's 269.5MB
    uint32_t* qpk    = kbar0p + kb0sz;
    uint32_t* kpk    = qpk + big;
    const size_t need_full = (2*big + kb0sz + 2*big) * 4ull;   // ~513 MiB
    if(ws_size < need_full){ qpk = nullptr; kpk = nullptr; }

    kbar0_kernel<<<dim3(MM, BH), 256, 0, stream>>>(K, kbar0p, kpk);
    // step 0 (writes Qpk if available)
    l_kernel<<<dim3(BBS, BH), 256, 0, stream>>>(Q, kbar0p, 0, nullptr, qpk, qbar);
    r_kernel<<<dim3(MM, BH), 512, 0, stream>>>(qbar, K, kpk, nullptr, kbar, 0);
    // step 1
    l_kernel<<<dim3(BBS, BH), 256, 0, stream>>>(Q, kbar, 1, qpk, nullptr, qbar);
    r_kernel<<<dim3(MM, BH), 512, 0, stream>>>(qbar, K, kpk, nullptr, kbar, 0);
    // step 2
    l_kernel<<<dim3(BBS, BH), 256, 0, stream>>>(Q, kbar, 1, qpk, nullptr, qbar);
    r_kernel<<<dim3(MM, BH), 512, 0, stream>>>(qbar, K, kpk, V, (uint32_t*)out, 1);  // Vbar
    // epilogue: recompute L3, out = L3 @ Vbar
    out_kernel<<<dim3(BBS, BH), 256, 0, stream>>>(Q, qpk, kbar, out);
}